// Round 5
// baseline (49.502 us; speedup 1.0000x reference)
//
#include <hip/hip_runtime.h>

// Problem constants (fixed by the reference)
constexpr int N    = 16384;
constexpr int K    = 32;
constexpr int D    = 128;
constexpr int SPAD = K + 4;       // padded LDS row (36) to break bank conflicts

// ------------------------------------------------------------------
// Stage 1: per-block partial E_b = T_b - S_b * c  -> ws[block][K*D]
// ROWS1=16 rows per block, grid = N/16 = 1024 blocks (4 blocks/CU,
// 4 waves/SIMD). x read directly from global: within a wave the 8
// lanes sharing a dc read the SAME address (coalesced to 1 request),
// and the 4x block-level reuse hits L1/L2.
// ------------------------------------------------------------------
constexpr int ROWS1 = 16;
constexpr int GRID1 = N / ROWS1;  // 1024

__global__ __launch_bounds__(256) void enc_partial(
    const float* __restrict__ x,      // (N, D)
    const float* __restrict__ codes,  // (K, D)
    const float* __restrict__ scale,  // (K,)
    float* __restrict__ ws)           // (GRID1, K*D)
{
    __shared__ float sc_lds[ROWS1][SPAD];  // raw scores l2*scale
    __shared__ float w_lds[ROWS1][SPAD];   // softmax weights

    const int tid = threadIdx.x;
    const int k   = tid >> 3;   // 0..31  (codeword owned by this thread)
    const int dc  = tid & 7;    // 0..7   (d-chunk owned)
    const int d0  = dc << 4;    // 16 floats per chunk

    // codes fragment for (k, d0..d0+15) in registers for the whole kernel
    const float4 ck0 = *reinterpret_cast<const float4*>(&codes[k * D + d0 + 0]);
    const float4 ck1 = *reinterpret_cast<const float4*>(&codes[k * D + d0 + 4]);
    const float4 ck2 = *reinterpret_cast<const float4*>(&codes[k * D + d0 + 8]);
    const float4 ck3 = *reinterpret_cast<const float4*>(&codes[k * D + d0 + 12]);
    const float scl = scale[k];

    const float* xb = x + (long)blockIdx.x * ROWS1 * D + d0;

    // ---------------- Phase 1: scores[n][k] = ||x_n - c_k|| * scale[k] ----------------
    // 4 independent accumulators break the dependent-fma chain (4cyc latency each).
    #pragma unroll 4
    for (int n = 0; n < ROWS1; ++n) {
        const float4* xr = reinterpret_cast<const float4*>(xb + (long)n * D);
        float4 x0 = xr[0], x1 = xr[1], x2 = xr[2], x3 = xr[3];
        float p0 = 0.f, p1 = 0.f, p2 = 0.f, p3 = 0.f, r;
        r = x0.x - ck0.x; p0 = fmaf(r, r, p0);
        r = x0.y - ck0.y; p1 = fmaf(r, r, p1);
        r = x0.z - ck0.z; p2 = fmaf(r, r, p2);
        r = x0.w - ck0.w; p3 = fmaf(r, r, p3);
        r = x1.x - ck1.x; p0 = fmaf(r, r, p0);
        r = x1.y - ck1.y; p1 = fmaf(r, r, p1);
        r = x1.z - ck1.z; p2 = fmaf(r, r, p2);
        r = x1.w - ck1.w; p3 = fmaf(r, r, p3);
        r = x2.x - ck2.x; p0 = fmaf(r, r, p0);
        r = x2.y - ck2.y; p1 = fmaf(r, r, p1);
        r = x2.z - ck2.z; p2 = fmaf(r, r, p2);
        r = x2.w - ck2.w; p3 = fmaf(r, r, p3);
        r = x3.x - ck3.x; p0 = fmaf(r, r, p0);
        r = x3.y - ck3.y; p1 = fmaf(r, r, p1);
        r = x3.z - ck3.z; p2 = fmaf(r, r, p2);
        r = x3.w - ck3.w; p3 = fmaf(r, r, p3);
        float p = (p0 + p1) + (p2 + p3);
        // reduce over the 8 contiguous lanes sharing this k
        p += __shfl_xor(p, 1);
        p += __shfl_xor(p, 2);
        p += __shfl_xor(p, 4);
        if (dc == 0) sc_lds[n][k] = sqrtf(p) * scl;
    }
    __syncthreads();

    // ---------------- Softmax over K per row: 16 threads/row, 2 k's each ----------------
    {
        const int row = tid >> 4;      // 0..15
        const int q   = tid & 15;
        float s0 = sc_lds[row][q];
        float s1 = sc_lds[row][q + 16];
        float m = fmaxf(s0, s1);
        m = fmaxf(m, __shfl_xor(m, 1));
        m = fmaxf(m, __shfl_xor(m, 2));
        m = fmaxf(m, __shfl_xor(m, 4));
        m = fmaxf(m, __shfl_xor(m, 8));
        const float LOG2E = 1.44269504088896f;
        float e0 = exp2f((s0 - m) * LOG2E);
        float e1 = exp2f((s1 - m) * LOG2E);
        float sum = e0 + e1;
        sum += __shfl_xor(sum, 1);
        sum += __shfl_xor(sum, 2);
        sum += __shfl_xor(sum, 4);
        sum += __shfl_xor(sum, 8);
        float inv = 1.0f / sum;
        w_lds[row][q]      = e0 * inv;
        w_lds[row][q + 16] = e1 * inv;
    }
    __syncthreads();

    // ---------------- Phase 2: T[k,d] = sum_n w*x ; S[k] = sum_n w ----------------
    float4 t0 = make_float4(0.f, 0.f, 0.f, 0.f);
    float4 t1 = t0, t2 = t0, t3 = t0;
    float sw = 0.f;
    #pragma unroll 4
    for (int n = 0; n < ROWS1; ++n) {
        float w = w_lds[n][k];
        const float4* xr = reinterpret_cast<const float4*>(xb + (long)n * D);
        float4 x0 = xr[0], x1 = xr[1], x2 = xr[2], x3 = xr[3];
        t0.x = fmaf(w, x0.x, t0.x);
        t0.y = fmaf(w, x0.y, t0.y);
        t0.z = fmaf(w, x0.z, t0.z);
        t0.w = fmaf(w, x0.w, t0.w);
        t1.x = fmaf(w, x1.x, t1.x);
        t1.y = fmaf(w, x1.y, t1.y);
        t1.z = fmaf(w, x1.z, t1.z);
        t1.w = fmaf(w, x1.w, t1.w);
        t2.x = fmaf(w, x2.x, t2.x);
        t2.y = fmaf(w, x2.y, t2.y);
        t2.z = fmaf(w, x2.z, t2.z);
        t2.w = fmaf(w, x2.w, t2.w);
        t3.x = fmaf(w, x3.x, t3.x);
        t3.y = fmaf(w, x3.y, t3.y);
        t3.z = fmaf(w, x3.z, t3.z);
        t3.w = fmaf(w, x3.w, t3.w);
        sw += w;
    }

    // ---------------- Epilogue: partial E_b = T - S*c -> ws (plain stores) ----------------
    // Note: k*D + d0 == tid*16, so each thread's 16 floats are contiguous.
    float* o = ws + (long)blockIdx.x * (K * D) + tid * 16;
    reinterpret_cast<float4*>(o)[0] = make_float4(t0.x - sw * ck0.x, t0.y - sw * ck0.y,
                                                  t0.z - sw * ck0.z, t0.w - sw * ck0.w);
    reinterpret_cast<float4*>(o)[1] = make_float4(t1.x - sw * ck1.x, t1.y - sw * ck1.y,
                                                  t1.z - sw * ck1.z, t1.w - sw * ck1.w);
    reinterpret_cast<float4*>(o)[2] = make_float4(t2.x - sw * ck2.x, t2.y - sw * ck2.y,
                                                  t2.z - sw * ck2.z, t2.w - sw * ck2.w);
    reinterpret_cast<float4*>(o)[3] = make_float4(t3.x - sw * ck3.x, t3.y - sw * ck3.y,
                                                  t3.z - sw * ck3.z, t3.w - sw * ck3.w);
}

// ------------------------------------------------------------------
// Stage 2: column-sum ws[1024][4096] -> out[4096].
// 256 blocks (full chip); block owns 4 float4-columns x all 1024 rows.
// Thread: col = tid&3, slice = tid>>2 (64 slices x 16 rows).
// LDS tree-combine; tid<4 store. No atomics, no pre-zero.
// ------------------------------------------------------------------
__global__ __launch_bounds__(256) void reduce2(
    const float* __restrict__ ws, float* __restrict__ out)
{
    __shared__ float4 part[64][4];     // 4 KB

    const int tid   = threadIdx.x;
    const int col   = tid & 3;                   // f4-col within block
    const int slice = tid >> 2;                  // 0..63, 16 rows each
    const int gcol  = blockIdx.x * 4 + col;      // 0..1023 (float4 columns)

    const float4* P = reinterpret_cast<const float4*>(ws);  // [1024][1024]
    float4 acc = make_float4(0.f, 0.f, 0.f, 0.f);
    #pragma unroll
    for (int r = 0; r < 16; ++r) {
        float4 v = P[(long)(slice * 16 + r) * 1024 + gcol];
        acc.x += v.x; acc.y += v.y; acc.z += v.z; acc.w += v.w;
    }
    part[slice][col] = acc;
    __syncthreads();

    // tree-reduce the 64 slices per column
    #pragma unroll
    for (int stride = 32; stride >= 1; stride >>= 1) {
        if (tid < stride * 4) {
            float4 a = part[slice][col];
            float4 b = part[slice + stride][col];
            a.x += b.x; a.y += b.y; a.z += b.z; a.w += b.w;
            part[slice][col] = a;
        }
        __syncthreads();
    }
    if (tid < 4) {
        reinterpret_cast<float4*>(out)[blockIdx.x * 4 + tid] = part[0][tid];
    }
}

// ------------------------------------------------------------------
// Fallback (ws too small): direct-atomic kernel, 256 blocks.
// Needs out pre-zeroed (memset only on this path).
// ------------------------------------------------------------------
constexpr int ROWSF = 64;

__global__ __launch_bounds__(256) void enc_atomic(
    const float* __restrict__ x,
    const float* __restrict__ codes,
    const float* __restrict__ scale,
    float* __restrict__ out)
{
    __shared__ float sc_lds[ROWSF][SPAD];
    __shared__ float w_lds[ROWSF][SPAD];

    const int tid = threadIdx.x;
    const int k   = tid >> 3;
    const int dc  = tid & 7;
    const int d0  = dc << 4;

    const float4 ck0 = *reinterpret_cast<const float4*>(&codes[k * D + d0 + 0]);
    const float4 ck1 = *reinterpret_cast<const float4*>(&codes[k * D + d0 + 4]);
    const float4 ck2 = *reinterpret_cast<const float4*>(&codes[k * D + d0 + 8]);
    const float4 ck3 = *reinterpret_cast<const float4*>(&codes[k * D + d0 + 12]);
    const float scl = scale[k];

    const float* xb = x + (long)blockIdx.x * ROWSF * D + d0;

    #pragma unroll 4
    for (int n = 0; n < ROWSF; ++n) {
        const float4* xr = reinterpret_cast<const float4*>(xb + (long)n * D);
        float4 x0 = xr[0], x1 = xr[1], x2 = xr[2], x3 = xr[3];
        float p = 0.f, r;
        r = x0.x - ck0.x; p = fmaf(r, r, p);
        r = x0.y - ck0.y; p = fmaf(r, r, p);
        r = x0.z - ck0.z; p = fmaf(r, r, p);
        r = x0.w - ck0.w; p = fmaf(r, r, p);
        r = x1.x - ck1.x; p = fmaf(r, r, p);
        r = x1.y - ck1.y; p = fmaf(r, r, p);
        r = x1.z - ck1.z; p = fmaf(r, r, p);
        r = x1.w - ck1.w; p = fmaf(r, r, p);
        r = x2.x - ck2.x; p = fmaf(r, r, p);
        r = x2.y - ck2.y; p = fmaf(r, r, p);
        r = x2.z - ck2.z; p = fmaf(r, r, p);
        r = x2.w - ck2.w; p = fmaf(r, r, p);
        r = x3.x - ck3.x; p = fmaf(r, r, p);
        r = x3.y - ck3.y; p = fmaf(r, r, p);
        r = x3.z - ck3.z; p = fmaf(r, r, p);
        r = x3.w - ck3.w; p = fmaf(r, r, p);
        p += __shfl_xor(p, 1);
        p += __shfl_xor(p, 2);
        p += __shfl_xor(p, 4);
        if (dc == 0) sc_lds[n][k] = sqrtf(p) * scl;
    }
    __syncthreads();

    {
        const int row = tid >> 2;
        const int q   = tid & 3;
        float4 s0 = *reinterpret_cast<const float4*>(&sc_lds[row][q * 8 + 0]);
        float4 s1 = *reinterpret_cast<const float4*>(&sc_lds[row][q * 8 + 4]);
        float m = fmaxf(fmaxf(fmaxf(s0.x, s0.y), fmaxf(s0.z, s0.w)),
                        fmaxf(fmaxf(s1.x, s1.y), fmaxf(s1.z, s1.w)));
        m = fmaxf(m, __shfl_xor(m, 1));
        m = fmaxf(m, __shfl_xor(m, 2));
        const float LOG2E = 1.44269504088896f;
        float e0 = exp2f((s0.x - m) * LOG2E);
        float e1 = exp2f((s0.y - m) * LOG2E);
        float e2 = exp2f((s0.z - m) * LOG2E);
        float e3 = exp2f((s0.w - m) * LOG2E);
        float e4 = exp2f((s1.x - m) * LOG2E);
        float e5 = exp2f((s1.y - m) * LOG2E);
        float e6 = exp2f((s1.z - m) * LOG2E);
        float e7 = exp2f((s1.w - m) * LOG2E);
        float sum = ((e0 + e1) + (e2 + e3)) + ((e4 + e5) + (e6 + e7));
        sum += __shfl_xor(sum, 1);
        sum += __shfl_xor(sum, 2);
        float inv = 1.0f / sum;
        *reinterpret_cast<float4*>(&w_lds[row][q * 8 + 0]) =
            make_float4(e0 * inv, e1 * inv, e2 * inv, e3 * inv);
        *reinterpret_cast<float4*>(&w_lds[row][q * 8 + 4]) =
            make_float4(e4 * inv, e5 * inv, e6 * inv, e7 * inv);
    }
    __syncthreads();

    float4 t0 = make_float4(0.f, 0.f, 0.f, 0.f);
    float4 t1 = t0, t2 = t0, t3 = t0;
    float sw = 0.f;
    #pragma unroll 4
    for (int n = 0; n < ROWSF; ++n) {
        float w = w_lds[n][k];
        const float4* xr = reinterpret_cast<const float4*>(xb + (long)n * D);
        float4 x0 = xr[0], x1 = xr[1], x2 = xr[2], x3 = xr[3];
        t0.x = fmaf(w, x0.x, t0.x);
        t0.y = fmaf(w, x0.y, t0.y);
        t0.z = fmaf(w, x0.z, t0.z);
        t0.w = fmaf(w, x0.w, t0.w);
        t1.x = fmaf(w, x1.x, t1.x);
        t1.y = fmaf(w, x1.y, t1.y);
        t1.z = fmaf(w, x1.z, t1.z);
        t1.w = fmaf(w, x1.w, t1.w);
        t2.x = fmaf(w, x2.x, t2.x);
        t2.y = fmaf(w, x2.y, t2.y);
        t2.z = fmaf(w, x2.z, t2.z);
        t2.w = fmaf(w, x2.w, t2.w);
        t3.x = fmaf(w, x3.x, t3.x);
        t3.y = fmaf(w, x3.y, t3.y);
        t3.z = fmaf(w, x3.z, t3.z);
        t3.w = fmaf(w, x3.w, t3.w);
        sw += w;
    }

    float* o = out + k * D + d0;
    atomicAdd(&o[0],  t0.x - sw * ck0.x);
    atomicAdd(&o[1],  t0.y - sw * ck0.y);
    atomicAdd(&o[2],  t0.z - sw * ck0.z);
    atomicAdd(&o[3],  t0.w - sw * ck0.w);
    atomicAdd(&o[4],  t1.x - sw * ck1.x);
    atomicAdd(&o[5],  t1.y - sw * ck1.y);
    atomicAdd(&o[6],  t1.z - sw * ck1.z);
    atomicAdd(&o[7],  t1.w - sw * ck1.w);
    atomicAdd(&o[8],  t2.x - sw * ck2.x);
    atomicAdd(&o[9],  t2.y - sw * ck2.y);
    atomicAdd(&o[10], t2.z - sw * ck2.z);
    atomicAdd(&o[11], t2.w - sw * ck2.w);
    atomicAdd(&o[12], t3.x - sw * ck3.x);
    atomicAdd(&o[13], t3.y - sw * ck3.y);
    atomicAdd(&o[14], t3.z - sw * ck3.z);
    atomicAdd(&o[15], t3.w - sw * ck3.w);
}

extern "C" void kernel_launch(void* const* d_in, const int* in_sizes, int n_in,
                              void* d_out, int out_size, void* d_ws, size_t ws_size,
                              hipStream_t stream) {
    const float* x     = (const float*)d_in[0];
    const float* codes = (const float*)d_in[1];
    const float* scale = (const float*)d_in[2];
    float* out = (float*)d_out;

    const size_t ws_needed = (size_t)GRID1 * K * D * sizeof(float);  // 16 MB
    if (ws_size >= ws_needed) {
        float* ws = (float*)d_ws;
        enc_partial<<<GRID1, 256, 0, stream>>>(x, codes, scale, ws);
        reduce2<<<256, 256, 0, stream>>>(ws, out);
    } else {
        hipMemsetAsync(out, 0, K * D * sizeof(float), stream);
        enc_atomic<<<N / ROWSF, 256, 0, stream>>>(x, codes, scale, out);
    }
}

// Round 6
// 31.350 us; speedup vs baseline: 1.5790x; 1.5790x over previous
//
#include <hip/hip_runtime.h>

// Problem constants (fixed by the reference)
constexpr int N    = 16384;
constexpr int K    = 32;
constexpr int D    = 128;
constexpr int SPAD = K + 4;       // padded LDS score row (36)

// ------------------------------------------------------------------
// Stage 1: per-block partial E_b = T_b - S_b * c  -> ws[block][K*D]
// ROWS1=16 rows/block, grid=1024 (4 blocks/CU, 4 waves/SIMD).
// Thread = (kg, dg): owns k in {2kg,2kg+1}, d in {4dg..+3} u {64+4dg..+3}.
// x tile staged once in LDS; all tile reads are dense 16-B-stride
// float4s -> conflict-free; x LDS volume halved vs (1k x 16d) layout.
// ------------------------------------------------------------------
constexpr int ROWS1 = 16;
constexpr int GRID1 = N / ROWS1;  // 1024

__global__ __launch_bounds__(256) void enc_partial(
    const float* __restrict__ x,      // (N, D)
    const float* __restrict__ codes,  // (K, D)
    const float* __restrict__ scale,  // (K,)
    float* __restrict__ ws)           // (GRID1, K*D)
{
    __shared__ float xs[ROWS1][D];         // 8 KB x tile
    __shared__ float sc_lds[ROWS1][SPAD];  // raw scores l2*scale
    __shared__ float w_lds[ROWS1][SPAD];   // softmax weights

    const int tid = threadIdx.x;
    const int kg  = tid >> 4;    // 0..15 -> k0 = 2kg, k1 = 2kg+1
    const int dg  = tid & 15;    // 0..15
    const int d4  = dg << 2;     // first float4 at d4, second at 64+d4
    const int k0  = kg << 1;

    // ---- stage x tile: 16 rows x 128 floats = 512 float4, 2 per thread ----
    {
        const float4* xg = reinterpret_cast<const float4*>(x + (long)blockIdx.x * ROWS1 * D);
        float4* xs4 = reinterpret_cast<float4*>(&xs[0][0]);
        xs4[tid]       = xg[tid];
        xs4[tid + 256] = xg[tid + 256];
    }

    // codes fragments (2 k's x 2 float4s) + scales in registers
    const float4 cA0 = *reinterpret_cast<const float4*>(&codes[k0 * D + d4]);
    const float4 cA1 = *reinterpret_cast<const float4*>(&codes[k0 * D + 64 + d4]);
    const float4 cB0 = *reinterpret_cast<const float4*>(&codes[(k0 + 1) * D + d4]);
    const float4 cB1 = *reinterpret_cast<const float4*>(&codes[(k0 + 1) * D + 64 + d4]);
    const float sA = scale[k0];
    const float sB = scale[k0 + 1];

    __syncthreads();

    // ---------------- Phase 1: scores[n][k] = ||x_n - c_k|| * scale[k] ----------------
    #pragma unroll 4
    for (int n = 0; n < ROWS1; ++n) {
        const float4 xa = *reinterpret_cast<const float4*>(&xs[n][d4]);
        const float4 xb = *reinterpret_cast<const float4*>(&xs[n][64 + d4]);
        float r;
        // 4 independent chains (2 per k) for ILP
        float pA0 = 0.f, pA1 = 0.f, pB0 = 0.f, pB1 = 0.f;
        r = xa.x - cA0.x; pA0 = fmaf(r, r, pA0);
        r = xa.y - cA0.y; pA1 = fmaf(r, r, pA1);
        r = xa.z - cA0.z; pA0 = fmaf(r, r, pA0);
        r = xa.w - cA0.w; pA1 = fmaf(r, r, pA1);
        r = xb.x - cA1.x; pA0 = fmaf(r, r, pA0);
        r = xb.y - cA1.y; pA1 = fmaf(r, r, pA1);
        r = xb.z - cA1.z; pA0 = fmaf(r, r, pA0);
        r = xb.w - cA1.w; pA1 = fmaf(r, r, pA1);
        r = xa.x - cB0.x; pB0 = fmaf(r, r, pB0);
        r = xa.y - cB0.y; pB1 = fmaf(r, r, pB1);
        r = xa.z - cB0.z; pB0 = fmaf(r, r, pB0);
        r = xa.w - cB0.w; pB1 = fmaf(r, r, pB1);
        r = xb.x - cB1.x; pB0 = fmaf(r, r, pB0);
        r = xb.y - cB1.y; pB1 = fmaf(r, r, pB1);
        r = xb.z - cB1.z; pB0 = fmaf(r, r, pB0);
        r = xb.w - cB1.w; pB1 = fmaf(r, r, pB1);
        float pA = pA0 + pA1;
        float pB = pB0 + pB1;
        // reduce over the 16 contiguous dg lanes (xor 1,2 -> DPP; 4,8 -> swizzle)
        pA += __shfl_xor(pA, 1);  pB += __shfl_xor(pB, 1);
        pA += __shfl_xor(pA, 2);  pB += __shfl_xor(pB, 2);
        pA += __shfl_xor(pA, 4);  pB += __shfl_xor(pB, 4);
        pA += __shfl_xor(pA, 8);  pB += __shfl_xor(pB, 8);
        if (dg == 0) {
            sc_lds[n][k0]     = sqrtf(pA) * sA;
            sc_lds[n][k0 + 1] = sqrtf(pB) * sB;
        }
    }
    __syncthreads();

    // ---------------- Softmax over K per row: 16 threads/row, 2 k's each ----------------
    {
        const int row = tid >> 4;      // 0..15
        const int q   = tid & 15;
        float s0 = sc_lds[row][q];
        float s1 = sc_lds[row][q + 16];
        float m = fmaxf(s0, s1);
        m = fmaxf(m, __shfl_xor(m, 1));
        m = fmaxf(m, __shfl_xor(m, 2));
        m = fmaxf(m, __shfl_xor(m, 4));
        m = fmaxf(m, __shfl_xor(m, 8));
        const float LOG2E = 1.44269504088896f;
        float e0 = exp2f((s0 - m) * LOG2E);
        float e1 = exp2f((s1 - m) * LOG2E);
        float sum = e0 + e1;
        sum += __shfl_xor(sum, 1);
        sum += __shfl_xor(sum, 2);
        sum += __shfl_xor(sum, 4);
        sum += __shfl_xor(sum, 8);
        float inv = 1.0f / sum;
        w_lds[row][q]      = e0 * inv;
        w_lds[row][q + 16] = e1 * inv;
    }
    __syncthreads();

    // ---------------- Phase 2: T[k,d] = sum_n w*x ; S[k] = sum_n w ----------------
    float4 tA0 = make_float4(0.f, 0.f, 0.f, 0.f);
    float4 tA1 = tA0, tB0 = tA0, tB1 = tA0;
    float swA = 0.f, swB = 0.f;
    #pragma unroll 4
    for (int n = 0; n < ROWS1; ++n) {
        const float2 w = *reinterpret_cast<const float2*>(&w_lds[n][k0]);  // b64, broadcast
        const float4 xa = *reinterpret_cast<const float4*>(&xs[n][d4]);
        const float4 xb = *reinterpret_cast<const float4*>(&xs[n][64 + d4]);
        tA0.x = fmaf(w.x, xa.x, tA0.x);
        tA0.y = fmaf(w.x, xa.y, tA0.y);
        tA0.z = fmaf(w.x, xa.z, tA0.z);
        tA0.w = fmaf(w.x, xa.w, tA0.w);
        tA1.x = fmaf(w.x, xb.x, tA1.x);
        tA1.y = fmaf(w.x, xb.y, tA1.y);
        tA1.z = fmaf(w.x, xb.z, tA1.z);
        tA1.w = fmaf(w.x, xb.w, tA1.w);
        tB0.x = fmaf(w.y, xa.x, tB0.x);
        tB0.y = fmaf(w.y, xa.y, tB0.y);
        tB0.z = fmaf(w.y, xa.z, tB0.z);
        tB0.w = fmaf(w.y, xa.w, tB0.w);
        tB1.x = fmaf(w.y, xb.x, tB1.x);
        tB1.y = fmaf(w.y, xb.y, tB1.y);
        tB1.z = fmaf(w.y, xb.z, tB1.z);
        tB1.w = fmaf(w.y, xb.w, tB1.w);
        swA += w.x;
        swB += w.y;
    }

    // ---------------- Epilogue: partial E_b = T - S*c -> ws (dense stores) ----------------
    float* o = ws + (long)blockIdx.x * (K * D) + k0 * D + d4;
    reinterpret_cast<float4*>(o)[0] = make_float4(tA0.x - swA * cA0.x, tA0.y - swA * cA0.y,
                                                  tA0.z - swA * cA0.z, tA0.w - swA * cA0.w);
    *reinterpret_cast<float4*>(o + 64) = make_float4(tA1.x - swA * cA1.x, tA1.y - swA * cA1.y,
                                                     tA1.z - swA * cA1.z, tA1.w - swA * cA1.w);
    *reinterpret_cast<float4*>(o + 128) = make_float4(tB0.x - swB * cB0.x, tB0.y - swB * cB0.y,
                                                      tB0.z - swB * cB0.z, tB0.w - swB * cB0.w);
    *reinterpret_cast<float4*>(o + 192) = make_float4(tB1.x - swB * cB1.x, tB1.y - swB * cB1.y,
                                                      tB1.z - swB * cB1.z, tB1.w - swB * cB1.w);
}

// ------------------------------------------------------------------
// Stage 2: column-sum ws[1024][4096] -> out[4096].
// 256 blocks (full chip); block owns 4 float4-columns x all 1024 rows.
// LDS tree-combine; tid<4 store. No atomics, no pre-zero.
// ------------------------------------------------------------------
__global__ __launch_bounds__(256) void reduce2(
    const float* __restrict__ ws, float* __restrict__ out)
{
    __shared__ float4 part[64][4];     // 4 KB

    const int tid   = threadIdx.x;
    const int col   = tid & 3;                   // f4-col within block
    const int slice = tid >> 2;                  // 0..63, 16 rows each
    const int gcol  = blockIdx.x * 4 + col;      // 0..1023 (float4 columns)

    const float4* P = reinterpret_cast<const float4*>(ws);  // [1024][1024]
    float4 acc = make_float4(0.f, 0.f, 0.f, 0.f);
    #pragma unroll
    for (int r = 0; r < 16; ++r) {
        float4 v = P[(long)(slice * 16 + r) * 1024 + gcol];
        acc.x += v.x; acc.y += v.y; acc.z += v.z; acc.w += v.w;
    }
    part[slice][col] = acc;
    __syncthreads();

    #pragma unroll
    for (int stride = 32; stride >= 1; stride >>= 1) {
        if (tid < stride * 4) {
            float4 a = part[slice][col];
            float4 b = part[slice + stride][col];
            a.x += b.x; a.y += b.y; a.z += b.z; a.w += b.w;
            part[slice][col] = a;
        }
        __syncthreads();
    }
    if (tid < 4) {
        reinterpret_cast<float4*>(out)[blockIdx.x * 4 + tid] = part[0][tid];
    }
}

// ------------------------------------------------------------------
// Fallback (ws too small): direct-atomic kernel, 256 blocks.
// Needs out pre-zeroed (memset only on this path).
// ------------------------------------------------------------------
constexpr int ROWSF = 64;

__global__ __launch_bounds__(256) void enc_atomic(
    const float* __restrict__ x,
    const float* __restrict__ codes,
    const float* __restrict__ scale,
    float* __restrict__ out)
{
    __shared__ float sc_lds[ROWSF][SPAD];
    __shared__ float w_lds[ROWSF][SPAD];

    const int tid = threadIdx.x;
    const int k   = tid >> 3;
    const int dc  = tid & 7;
    const int d0  = dc << 4;

    const float4 ck0 = *reinterpret_cast<const float4*>(&codes[k * D + d0 + 0]);
    const float4 ck1 = *reinterpret_cast<const float4*>(&codes[k * D + d0 + 4]);
    const float4 ck2 = *reinterpret_cast<const float4*>(&codes[k * D + d0 + 8]);
    const float4 ck3 = *reinterpret_cast<const float4*>(&codes[k * D + d0 + 12]);
    const float scl = scale[k];

    const float* xb = x + (long)blockIdx.x * ROWSF * D + d0;

    #pragma unroll 4
    for (int n = 0; n < ROWSF; ++n) {
        const float4* xr = reinterpret_cast<const float4*>(xb + (long)n * D);
        float4 x0 = xr[0], x1 = xr[1], x2 = xr[2], x3 = xr[3];
        float p = 0.f, r;
        r = x0.x - ck0.x; p = fmaf(r, r, p);
        r = x0.y - ck0.y; p = fmaf(r, r, p);
        r = x0.z - ck0.z; p = fmaf(r, r, p);
        r = x0.w - ck0.w; p = fmaf(r, r, p);
        r = x1.x - ck1.x; p = fmaf(r, r, p);
        r = x1.y - ck1.y; p = fmaf(r, r, p);
        r = x1.z - ck1.z; p = fmaf(r, r, p);
        r = x1.w - ck1.w; p = fmaf(r, r, p);
        r = x2.x - ck2.x; p = fmaf(r, r, p);
        r = x2.y - ck2.y; p = fmaf(r, r, p);
        r = x2.z - ck2.z; p = fmaf(r, r, p);
        r = x2.w - ck2.w; p = fmaf(r, r, p);
        r = x3.x - ck3.x; p = fmaf(r, r, p);
        r = x3.y - ck3.y; p = fmaf(r, r, p);
        r = x3.z - ck3.z; p = fmaf(r, r, p);
        r = x3.w - ck3.w; p = fmaf(r, r, p);
        p += __shfl_xor(p, 1);
        p += __shfl_xor(p, 2);
        p += __shfl_xor(p, 4);
        if (dc == 0) sc_lds[n][k] = sqrtf(p) * scl;
    }
    __syncthreads();

    {
        const int row = tid >> 2;
        const int q   = tid & 3;
        float4 s0 = *reinterpret_cast<const float4*>(&sc_lds[row][q * 8 + 0]);
        float4 s1 = *reinterpret_cast<const float4*>(&sc_lds[row][q * 8 + 4]);
        float m = fmaxf(fmaxf(fmaxf(s0.x, s0.y), fmaxf(s0.z, s0.w)),
                        fmaxf(fmaxf(s1.x, s1.y), fmaxf(s1.z, s1.w)));
        m = fmaxf(m, __shfl_xor(m, 1));
        m = fmaxf(m, __shfl_xor(m, 2));
        const float LOG2E = 1.44269504088896f;
        float e0 = exp2f((s0.x - m) * LOG2E);
        float e1 = exp2f((s0.y - m) * LOG2E);
        float e2 = exp2f((s0.z - m) * LOG2E);
        float e3 = exp2f((s0.w - m) * LOG2E);
        float e4 = exp2f((s1.x - m) * LOG2E);
        float e5 = exp2f((s1.y - m) * LOG2E);
        float e6 = exp2f((s1.z - m) * LOG2E);
        float e7 = exp2f((s1.w - m) * LOG2E);
        float sum = ((e0 + e1) + (e2 + e3)) + ((e4 + e5) + (e6 + e7));
        sum += __shfl_xor(sum, 1);
        sum += __shfl_xor(sum, 2);
        float inv = 1.0f / sum;
        *reinterpret_cast<float4*>(&w_lds[row][q * 8 + 0]) =
            make_float4(e0 * inv, e1 * inv, e2 * inv, e3 * inv);
        *reinterpret_cast<float4*>(&w_lds[row][q * 8 + 4]) =
            make_float4(e4 * inv, e5 * inv, e6 * inv, e7 * inv);
    }
    __syncthreads();

    float4 t0 = make_float4(0.f, 0.f, 0.f, 0.f);
    float4 t1 = t0, t2 = t0, t3 = t0;
    float sw = 0.f;
    #pragma unroll 4
    for (int n = 0; n < ROWSF; ++n) {
        float w = w_lds[n][k];
        const float4* xr = reinterpret_cast<const float4*>(xb + (long)n * D);
        float4 x0 = xr[0], x1 = xr[1], x2 = xr[2], x3 = xr[3];
        t0.x = fmaf(w, x0.x, t0.x);
        t0.y = fmaf(w, x0.y, t0.y);
        t0.z = fmaf(w, x0.z, t0.z);
        t0.w = fmaf(w, x0.w, t0.w);
        t1.x = fmaf(w, x1.x, t1.x);
        t1.y = fmaf(w, x1.y, t1.y);
        t1.z = fmaf(w, x1.z, t1.z);
        t1.w = fmaf(w, x1.w, t1.w);
        t2.x = fmaf(w, x2.x, t2.x);
        t2.y = fmaf(w, x2.y, t2.y);
        t2.z = fmaf(w, x2.z, t2.z);
        t2.w = fmaf(w, x2.w, t2.w);
        t3.x = fmaf(w, x3.x, t3.x);
        t3.y = fmaf(w, x3.y, t3.y);
        t3.z = fmaf(w, x3.z, t3.z);
        t3.w = fmaf(w, x3.w, t3.w);
        sw += w;
    }

    float* o = out + k * D + d0;
    atomicAdd(&o[0],  t0.x - sw * ck0.x);
    atomicAdd(&o[1],  t0.y - sw * ck0.y);
    atomicAdd(&o[2],  t0.z - sw * ck0.z);
    atomicAdd(&o[3],  t0.w - sw * ck0.w);
    atomicAdd(&o[4],  t1.x - sw * ck1.x);
    atomicAdd(&o[5],  t1.y - sw * ck1.y);
    atomicAdd(&o[6],  t1.z - sw * ck1.z);
    atomicAdd(&o[7],  t1.w - sw * ck1.w);
    atomicAdd(&o[8],  t2.x - sw * ck2.x);
    atomicAdd(&o[9],  t2.y - sw * ck2.y);
    atomicAdd(&o[10], t2.z - sw * ck2.z);
    atomicAdd(&o[11], t2.w - sw * ck2.w);
    atomicAdd(&o[12], t3.x - sw * ck3.x);
    atomicAdd(&o[13], t3.y - sw * ck3.y);
    atomicAdd(&o[14], t3.z - sw * ck3.z);
    atomicAdd(&o[15], t3.w - sw * ck3.w);
}

extern "C" void kernel_launch(void* const* d_in, const int* in_sizes, int n_in,
                              void* d_out, int out_size, void* d_ws, size_t ws_size,
                              hipStream_t stream) {
    const float* x     = (const float*)d_in[0];
    const float* codes = (const float*)d_in[1];
    const float* scale = (const float*)d_in[2];
    float* out = (float*)d_out;

    const size_t ws_needed = (size_t)GRID1 * K * D * sizeof(float);  // 16 MB
    if (ws_size >= ws_needed) {
        float* ws = (float*)d_ws;
        enc_partial<<<GRID1, 256, 0, stream>>>(x, codes, scale, ws);
        reduce2<<<256, 256, 0, stream>>>(ws, out);
    } else {
        hipMemsetAsync(out, 0, K * D * sizeof(float), stream);
        enc_atomic<<<N / ROWSF, 256, 0, stream>>>(x, codes, scale, out);
    }
}

// Round 7
// 29.734 us; speedup vs baseline: 1.6648x; 1.0543x over previous
//
#include <hip/hip_runtime.h>

// Problem constants (fixed by the reference)
constexpr int N    = 16384;
constexpr int K    = 32;
constexpr int D    = 128;
constexpr int SPAD = K + 2;       // LDS score row stride (34)

// ---- DPP helpers: butterfly add over 16-lane groups, pure VALU ----
// quad_perm[1,0,3,2]=0xB1 (xor1), quad_perm[2,3,0,1]=0x4E (xor2),
// row_half_mirror=0x141 (pairs quads), row_mirror=0x140 (pairs octets).
template <int CTRL>
__device__ __forceinline__ float dpp_add(float v) {
    int j = __builtin_amdgcn_update_dpp(0, __float_as_int(v), CTRL, 0xF, 0xF, false);
    return v + __int_as_float(j);
}
__device__ __forceinline__ float sum16(float v) {
    v = dpp_add<0xB1>(v);
    v = dpp_add<0x4E>(v);
    v = dpp_add<0x141>(v);
    v = dpp_add<0x140>(v);
    return v;   // full 16-lane sum in every lane of the group
}

// ------------------------------------------------------------------
// Stage 1: per-block partial E_b = T_b - S_b * c  -> ws[block][K*D]
// ROWS1=8 rows/block, grid = 2048. Thread (kg,dg) owns k in {2kg,2kg+1},
// d in {4dg..4dg+3} u {64+4dg..}. x lives in REGISTERS (no LDS transit);
// distance reduce is DPP (no LDS pipe). LDS only for scores/weights.
// ------------------------------------------------------------------
constexpr int ROWS1 = 8;
constexpr int GRID1 = N / ROWS1;  // 2048

__global__ __launch_bounds__(256) void enc_partial(
    const float* __restrict__ x,      // (N, D)
    const float* __restrict__ codes,  // (K, D)
    const float* __restrict__ scale,  // (K,)
    float* __restrict__ ws)           // (GRID1, K*D)
{
    __shared__ float sc_lds[ROWS1][SPAD];  // raw scores l2*scale
    __shared__ float w_lds[ROWS1][SPAD];   // softmax weights

    const int tid = threadIdx.x;
    const int kg  = tid >> 4;    // 0..15 -> k0 = 2kg
    const int dg  = tid & 15;    // 0..15
    const int d4  = dg << 2;     // float4 at d4 and 64+d4
    const int k0  = kg << 1;

    // ---- x slice into registers: 8 rows x 2 float4 ----
    const float* xb = x + (long)blockIdx.x * ROWS1 * D;
    float4 xr[ROWS1][2];
    #pragma unroll
    for (int n = 0; n < ROWS1; ++n) {
        xr[n][0] = *reinterpret_cast<const float4*>(xb + n * D + d4);
        xr[n][1] = *reinterpret_cast<const float4*>(xb + n * D + 64 + d4);
    }

    // codes fragments (2 k's x 2 float4s) + scales
    const float4 cA0 = *reinterpret_cast<const float4*>(&codes[k0 * D + d4]);
    const float4 cA1 = *reinterpret_cast<const float4*>(&codes[k0 * D + 64 + d4]);
    const float4 cB0 = *reinterpret_cast<const float4*>(&codes[(k0 + 1) * D + d4]);
    const float4 cB1 = *reinterpret_cast<const float4*>(&codes[(k0 + 1) * D + 64 + d4]);
    const float sA = scale[k0];
    const float sB = scale[k0 + 1];

    // ---------------- Phase 1: scores[n][k] = ||x_n - c_k|| * scale[k] ----------------
    #pragma unroll
    for (int n = 0; n < ROWS1; ++n) {
        const float4 xa = xr[n][0];
        const float4 xb4 = xr[n][1];
        float r;
        float pA0 = 0.f, pA1 = 0.f, pB0 = 0.f, pB1 = 0.f;
        r = xa.x - cA0.x;  pA0 = fmaf(r, r, pA0);
        r = xa.y - cA0.y;  pA1 = fmaf(r, r, pA1);
        r = xa.z - cA0.z;  pA0 = fmaf(r, r, pA0);
        r = xa.w - cA0.w;  pA1 = fmaf(r, r, pA1);
        r = xb4.x - cA1.x; pA0 = fmaf(r, r, pA0);
        r = xb4.y - cA1.y; pA1 = fmaf(r, r, pA1);
        r = xb4.z - cA1.z; pA0 = fmaf(r, r, pA0);
        r = xb4.w - cA1.w; pA1 = fmaf(r, r, pA1);
        r = xa.x - cB0.x;  pB0 = fmaf(r, r, pB0);
        r = xa.y - cB0.y;  pB1 = fmaf(r, r, pB1);
        r = xa.z - cB0.z;  pB0 = fmaf(r, r, pB0);
        r = xa.w - cB0.w;  pB1 = fmaf(r, r, pB1);
        r = xb4.x - cB1.x; pB0 = fmaf(r, r, pB0);
        r = xb4.y - cB1.y; pB1 = fmaf(r, r, pB1);
        r = xb4.z - cB1.z; pB0 = fmaf(r, r, pB0);
        r = xb4.w - cB1.w; pB1 = fmaf(r, r, pB1);
        float pA = sum16(pA0 + pA1);   // pure-VALU 16-lane reduce
        float pB = sum16(pB0 + pB1);
        if (dg == 0) {
            sc_lds[n][k0]     = sqrtf(pA) * sA;
            sc_lds[n][k0 + 1] = sqrtf(pB) * sB;
        }
    }
    __syncthreads();

    // ---------------- Softmax over K per row: 32 threads/row, 1 k each ----------------
    {
        const int row = tid >> 5;      // 0..7
        const int q   = tid & 31;
        float s = sc_lds[row][q];
        float m = s;
        m = fmaxf(m, __shfl_xor(m, 1));
        m = fmaxf(m, __shfl_xor(m, 2));
        m = fmaxf(m, __shfl_xor(m, 4));
        m = fmaxf(m, __shfl_xor(m, 8));
        m = fmaxf(m, __shfl_xor(m, 16));
        const float LOG2E = 1.44269504088896f;
        float e = exp2f((s - m) * LOG2E);
        float sum = e;
        sum += __shfl_xor(sum, 1);
        sum += __shfl_xor(sum, 2);
        sum += __shfl_xor(sum, 4);
        sum += __shfl_xor(sum, 8);
        sum += __shfl_xor(sum, 16);
        w_lds[row][q] = e * (1.0f / sum);
    }
    __syncthreads();

    // ---------------- Phase 2: T[k,d] = sum_n w*x ; S[k] = sum_n w (x from regs) ----------------
    float4 tA0 = make_float4(0.f, 0.f, 0.f, 0.f);
    float4 tA1 = tA0, tB0 = tA0, tB1 = tA0;
    float swA = 0.f, swB = 0.f;
    #pragma unroll
    for (int n = 0; n < ROWS1; ++n) {
        const float2 w = *reinterpret_cast<const float2*>(&w_lds[n][k0]);  // broadcast b64
        const float4 xa = xr[n][0];
        const float4 xb4 = xr[n][1];
        tA0.x = fmaf(w.x, xa.x, tA0.x);
        tA0.y = fmaf(w.x, xa.y, tA0.y);
        tA0.z = fmaf(w.x, xa.z, tA0.z);
        tA0.w = fmaf(w.x, xa.w, tA0.w);
        tA1.x = fmaf(w.x, xb4.x, tA1.x);
        tA1.y = fmaf(w.x, xb4.y, tA1.y);
        tA1.z = fmaf(w.x, xb4.z, tA1.z);
        tA1.w = fmaf(w.x, xb4.w, tA1.w);
        tB0.x = fmaf(w.y, xa.x, tB0.x);
        tB0.y = fmaf(w.y, xa.y, tB0.y);
        tB0.z = fmaf(w.y, xa.z, tB0.z);
        tB0.w = fmaf(w.y, xa.w, tB0.w);
        tB1.x = fmaf(w.y, xb4.x, tB1.x);
        tB1.y = fmaf(w.y, xb4.y, tB1.y);
        tB1.z = fmaf(w.y, xb4.z, tB1.z);
        tB1.w = fmaf(w.y, xb4.w, tB1.w);
        swA += w.x;
        swB += w.y;
    }

    // ---------------- Epilogue: partial E_b = T - S*c -> ws (dense stores) ----------------
    float* o = ws + (long)blockIdx.x * (K * D) + k0 * D + d4;
    *reinterpret_cast<float4*>(o)       = make_float4(tA0.x - swA * cA0.x, tA0.y - swA * cA0.y,
                                                      tA0.z - swA * cA0.z, tA0.w - swA * cA0.w);
    *reinterpret_cast<float4*>(o + 64)  = make_float4(tA1.x - swA * cA1.x, tA1.y - swA * cA1.y,
                                                      tA1.z - swA * cA1.z, tA1.w - swA * cA1.w);
    *reinterpret_cast<float4*>(o + 128) = make_float4(tB0.x - swB * cB0.x, tB0.y - swB * cB0.y,
                                                      tB0.z - swB * cB0.z, tB0.w - swB * cB0.w);
    *reinterpret_cast<float4*>(o + 192) = make_float4(tB1.x - swB * cB1.x, tB1.y - swB * cB1.y,
                                                      tB1.z - swB * cB1.z, tB1.w - swB * cB1.w);
}

// ------------------------------------------------------------------
// Stage 2: column-sum ws[2048][4096] -> out[4096].
// 128 blocks; block owns 8 contiguous float4-cols (= one full 128-B
// cache line) x all 2048 rows -> zero overfetch, coalesced wave loads.
// Thread: col = tid&7, slice = tid>>3 (32 slices x 64 rows).
// LDS tree-combine; tid<8 store. No atomics, no pre-zero.
// ------------------------------------------------------------------
__global__ __launch_bounds__(256) void reduce2(
    const float* __restrict__ ws, float* __restrict__ out)
{
    __shared__ float4 part[32][8];     // 4 KB

    const int tid   = threadIdx.x;
    const int col   = tid & 7;                   // f4-col within block
    const int slice = tid >> 3;                  // 0..31, 64 rows each
    const int gcol  = blockIdx.x * 8 + col;      // 0..1023 (float4 columns)

    const float4* P = reinterpret_cast<const float4*>(ws);  // [2048][1024]
    float4 acc = make_float4(0.f, 0.f, 0.f, 0.f);
    #pragma unroll 8
    for (int r = 0; r < 64; ++r) {
        float4 v = P[(long)(slice * 64 + r) * 1024 + gcol];
        acc.x += v.x; acc.y += v.y; acc.z += v.z; acc.w += v.w;
    }
    part[slice][col] = acc;
    __syncthreads();

    #pragma unroll
    for (int stride = 16; stride >= 1; stride >>= 1) {
        if (tid < stride * 8) {
            float4 a = part[slice][col];
            float4 b = part[slice + stride][col];
            a.x += b.x; a.y += b.y; a.z += b.z; a.w += b.w;
            part[slice][col] = a;
        }
        __syncthreads();
    }
    if (tid < 8) {
        reinterpret_cast<float4*>(out)[blockIdx.x * 8 + tid] = part[0][tid];
    }
}

// ------------------------------------------------------------------
// Fallback (ws too small): direct-atomic kernel, 256 blocks.
// Needs out pre-zeroed (memset only on this path).
// ------------------------------------------------------------------
constexpr int ROWSF = 64;
constexpr int FPAD  = K + 4;

__global__ __launch_bounds__(256) void enc_atomic(
    const float* __restrict__ x,
    const float* __restrict__ codes,
    const float* __restrict__ scale,
    float* __restrict__ out)
{
    __shared__ float sc_lds[ROWSF][FPAD];
    __shared__ float w_lds[ROWSF][FPAD];

    const int tid = threadIdx.x;
    const int k   = tid >> 3;
    const int dc  = tid & 7;
    const int d0  = dc << 4;

    const float4 ck0 = *reinterpret_cast<const float4*>(&codes[k * D + d0 + 0]);
    const float4 ck1 = *reinterpret_cast<const float4*>(&codes[k * D + d0 + 4]);
    const float4 ck2 = *reinterpret_cast<const float4*>(&codes[k * D + d0 + 8]);
    const float4 ck3 = *reinterpret_cast<const float4*>(&codes[k * D + d0 + 12]);
    const float scl = scale[k];

    const float* xb = x + (long)blockIdx.x * ROWSF * D + d0;

    #pragma unroll 4
    for (int n = 0; n < ROWSF; ++n) {
        const float4* xr = reinterpret_cast<const float4*>(xb + (long)n * D);
        float4 x0 = xr[0], x1 = xr[1], x2 = xr[2], x3 = xr[3];
        float p = 0.f, r;
        r = x0.x - ck0.x; p = fmaf(r, r, p);
        r = x0.y - ck0.y; p = fmaf(r, r, p);
        r = x0.z - ck0.z; p = fmaf(r, r, p);
        r = x0.w - ck0.w; p = fmaf(r, r, p);
        r = x1.x - ck1.x; p = fmaf(r, r, p);
        r = x1.y - ck1.y; p = fmaf(r, r, p);
        r = x1.z - ck1.z; p = fmaf(r, r, p);
        r = x1.w - ck1.w; p = fmaf(r, r, p);
        r = x2.x - ck2.x; p = fmaf(r, r, p);
        r = x2.y - ck2.y; p = fmaf(r, r, p);
        r = x2.z - ck2.z; p = fmaf(r, r, p);
        r = x2.w - ck2.w; p = fmaf(r, r, p);
        r = x3.x - ck3.x; p = fmaf(r, r, p);
        r = x3.y - ck3.y; p = fmaf(r, r, p);
        r = x3.z - ck3.z; p = fmaf(r, r, p);
        r = x3.w - ck3.w; p = fmaf(r, r, p);
        p += __shfl_xor(p, 1);
        p += __shfl_xor(p, 2);
        p += __shfl_xor(p, 4);
        if (dc == 0) sc_lds[n][k] = sqrtf(p) * scl;
    }
    __syncthreads();

    {
        const int row = tid >> 2;
        const int q   = tid & 3;
        float4 s0 = *reinterpret_cast<const float4*>(&sc_lds[row][q * 8 + 0]);
        float4 s1 = *reinterpret_cast<const float4*>(&sc_lds[row][q * 8 + 4]);
        float m = fmaxf(fmaxf(fmaxf(s0.x, s0.y), fmaxf(s0.z, s0.w)),
                        fmaxf(fmaxf(s1.x, s1.y), fmaxf(s1.z, s1.w)));
        m = fmaxf(m, __shfl_xor(m, 1));
        m = fmaxf(m, __shfl_xor(m, 2));
        const float LOG2E = 1.44269504088896f;
        float e0 = exp2f((s0.x - m) * LOG2E);
        float e1 = exp2f((s0.y - m) * LOG2E);
        float e2 = exp2f((s0.z - m) * LOG2E);
        float e3 = exp2f((s0.w - m) * LOG2E);
        float e4 = exp2f((s1.x - m) * LOG2E);
        float e5 = exp2f((s1.y - m) * LOG2E);
        float e6 = exp2f((s1.z - m) * LOG2E);
        float e7 = exp2f((s1.w - m) * LOG2E);
        float sum = ((e0 + e1) + (e2 + e3)) + ((e4 + e5) + (e6 + e7));
        sum += __shfl_xor(sum, 1);
        sum += __shfl_xor(sum, 2);
        float inv = 1.0f / sum;
        *reinterpret_cast<float4*>(&w_lds[row][q * 8 + 0]) =
            make_float4(e0 * inv, e1 * inv, e2 * inv, e3 * inv);
        *reinterpret_cast<float4*>(&w_lds[row][q * 8 + 4]) =
            make_float4(e4 * inv, e5 * inv, e6 * inv, e7 * inv);
    }
    __syncthreads();

    float4 t0 = make_float4(0.f, 0.f, 0.f, 0.f);
    float4 t1 = t0, t2 = t0, t3 = t0;
    float sw = 0.f;
    #pragma unroll 4
    for (int n = 0; n < ROWSF; ++n) {
        float w = w_lds[n][k];
        const float4* xr = reinterpret_cast<const float4*>(xb + (long)n * D);
        float4 x0 = xr[0], x1 = xr[1], x2 = xr[2], x3 = xr[3];
        t0.x = fmaf(w, x0.x, t0.x);
        t0.y = fmaf(w, x0.y, t0.y);
        t0.z = fmaf(w, x0.z, t0.z);
        t0.w = fmaf(w, x0.w, t0.w);
        t1.x = fmaf(w, x1.x, t1.x);
        t1.y = fmaf(w, x1.y, t1.y);
        t1.z = fmaf(w, x1.z, t1.z);
        t1.w = fmaf(w, x1.w, t1.w);
        t2.x = fmaf(w, x2.x, t2.x);
        t2.y = fmaf(w, x2.y, t2.y);
        t2.z = fmaf(w, x2.z, t2.z);
        t2.w = fmaf(w, x2.w, t2.w);
        t3.x = fmaf(w, x3.x, t3.x);
        t3.y = fmaf(w, x3.y, t3.y);
        t3.z = fmaf(w, x3.z, t3.z);
        t3.w = fmaf(w, x3.w, t3.w);
        sw += w;
    }

    float* o = out + k * D + d0;
    atomicAdd(&o[0],  t0.x - sw * ck0.x);
    atomicAdd(&o[1],  t0.y - sw * ck0.y);
    atomicAdd(&o[2],  t0.z - sw * ck0.z);
    atomicAdd(&o[3],  t0.w - sw * ck0.w);
    atomicAdd(&o[4],  t1.x - sw * ck1.x);
    atomicAdd(&o[5],  t1.y - sw * ck1.y);
    atomicAdd(&o[6],  t1.z - sw * ck1.z);
    atomicAdd(&o[7],  t1.w - sw * ck1.w);
    atomicAdd(&o[8],  t2.x - sw * ck2.x);
    atomicAdd(&o[9],  t2.y - sw * ck2.y);
    atomicAdd(&o[10], t2.z - sw * ck2.z);
    atomicAdd(&o[11], t2.w - sw * ck2.w);
    atomicAdd(&o[12], t3.x - sw * ck3.x);
    atomicAdd(&o[13], t3.y - sw * ck3.y);
    atomicAdd(&o[14], t3.z - sw * ck3.z);
    atomicAdd(&o[15], t3.w - sw * ck3.w);
}

extern "C" void kernel_launch(void* const* d_in, const int* in_sizes, int n_in,
                              void* d_out, int out_size, void* d_ws, size_t ws_size,
                              hipStream_t stream) {
    const float* x     = (const float*)d_in[0];
    const float* codes = (const float*)d_in[1];
    const float* scale = (const float*)d_in[2];
    float* out = (float*)d_out;

    const size_t ws_needed = (size_t)GRID1 * K * D * sizeof(float);  // 32 MB
    if (ws_size >= ws_needed) {
        float* ws = (float*)d_ws;
        enc_partial<<<GRID1, 256, 0, stream>>>(x, codes, scale, ws);
        reduce2<<<128, 256, 0, stream>>>(ws, out);
    } else {
        hipMemsetAsync(out, 0, K * D * sizeof(float), stream);
        enc_atomic<<<N / ROWSF, 256, 0, stream>>>(x, codes, scale, out);
    }
}